// Round 1
// baseline (502.807 us; speedup 1.0000x reference)
//
#include <hip/hip_runtime.h>
#include <cstdint>
#include <cstddef>

typedef __bf16 bhalf;
typedef __bf16 bhalf8 __attribute__((ext_vector_type(8)));
typedef __bf16 bhalf4 __attribute__((ext_vector_type(4)));
typedef float f32x4 __attribute__((ext_vector_type(4)));

#define RMS_EPS 1e-6f
#define N_HEADS 16
#define N_KV 4
#define HD 128
#define DIM 2048
#define SEQ 2048
#define BATCH 2

static __device__ __forceinline__ f32x4 mfma16(bhalf8 a, bhalf8 b, f32x4 c) {
    return __builtin_amdgcn_mfma_f32_16x16x32_bf16(a, b, c, 0, 0, 0);
}

// ---------------- weight convert f32 -> bf16 ----------------
__global__ __launch_bounds__(256) void cvt_w(const float* __restrict__ a,
                                             const float* __restrict__ b,
                                             bhalf* __restrict__ dst) {
    size_t i = ((size_t)blockIdx.x * 256 + threadIdx.x) * 4;
    const size_t NQ = (size_t)3072 * 2048;
    float4 v = (i < NQ) ? ((const float4*)a)[i >> 2] : ((const float4*)b)[(i - NQ) >> 2];
    bhalf4 o;
    o[0] = (bhalf)v.x; o[1] = (bhalf)v.y; o[2] = (bhalf)v.z; o[3] = (bhalf)v.w;
    *(bhalf4*)(dst + i) = o;
}

// ---------------- RMSNorm: one block per row ----------------
__global__ __launch_bounds__(256) void rmsnorm_k(const float* __restrict__ x,
                                                 const float* __restrict__ w,
                                                 bhalf* __restrict__ xn) {
    const int row = blockIdx.x;
    const int tid = threadIdx.x;
    const float4* xr = (const float4*)(x + (size_t)row * DIM);
    float4 v0 = xr[tid * 2], v1 = xr[tid * 2 + 1];
    float ss = v0.x * v0.x + v0.y * v0.y + v0.z * v0.z + v0.w * v0.w
             + v1.x * v1.x + v1.y * v1.y + v1.z * v1.z + v1.w * v1.w;
    #pragma unroll
    for (int off = 32; off; off >>= 1) ss += __shfl_xor(ss, off, 64);
    __shared__ float red[4];
    if ((tid & 63) == 0) red[tid >> 6] = ss;
    __syncthreads();
    float tot = red[0] + red[1] + red[2] + red[3];
    float scale = rsqrtf(tot * (1.0f / DIM) + RMS_EPS);
    const float4* wr = (const float4*)w;
    float4 w0 = wr[tid * 2], w1 = wr[tid * 2 + 1];
    bhalf8 o;
    o[0] = (bhalf)(v0.x * scale * w0.x); o[1] = (bhalf)(v0.y * scale * w0.y);
    o[2] = (bhalf)(v0.z * scale * w0.z); o[3] = (bhalf)(v0.w * scale * w0.w);
    o[4] = (bhalf)(v1.x * scale * w1.x); o[5] = (bhalf)(v1.y * scale * w1.y);
    o[6] = (bhalf)(v1.z * scale * w1.z); o[7] = (bhalf)(v1.w * scale * w1.w);
    *(bhalf8*)(xn + (size_t)row * DIM + tid * 8) = o;
}

// ---------------- GEMM C = A * B^T (both K-contiguous, bf16 in, f32 out) ---
// A: M x K, B: N x K, C: M x N.  Tile 128x128, BK=32, 4 waves (2x2 of 64x64).
__global__ __launch_bounds__(256) void gemm_abt(const bhalf* __restrict__ A,
                                                const bhalf* __restrict__ B,
                                                float* __restrict__ C,
                                                int N, int K) {
    const int tid = threadIdx.x;
    const int wave = tid >> 6, lane = tid & 63;
    const int quad = lane >> 4, r16 = lane & 15;
    const int m0 = blockIdx.y * 128, n0 = blockIdx.x * 128;
    const int wm = (wave >> 1) * 64, wn = (wave & 1) * 64;

    __shared__ __align__(16) bhalf sA[128][40];
    __shared__ __align__(16) bhalf sB[128][40];

    f32x4 acc[4][4];
    #pragma unroll
    for (int i = 0; i < 4; ++i)
        #pragma unroll
        for (int j = 0; j < 4; ++j) acc[i][j] = (f32x4)0.0f;

    const int lrow = tid >> 2, lcc = (tid & 3) * 8;
    const bhalf* a0p = A + (size_t)(m0 + lrow) * K + lcc;
    const bhalf* a1p = a0p + (size_t)64 * K;
    const bhalf* b0p = B + (size_t)(n0 + lrow) * K + lcc;
    const bhalf* b1p = b0p + (size_t)64 * K;

    for (int k0 = 0; k0 < K; k0 += 32) {
        bhalf8 a0 = *(const bhalf8*)(a0p + k0);
        bhalf8 a1 = *(const bhalf8*)(a1p + k0);
        bhalf8 b0 = *(const bhalf8*)(b0p + k0);
        bhalf8 b1 = *(const bhalf8*)(b1p + k0);
        __syncthreads();
        *(bhalf8*)&sA[lrow][lcc] = a0;
        *(bhalf8*)&sA[64 + lrow][lcc] = a1;
        *(bhalf8*)&sB[lrow][lcc] = b0;
        *(bhalf8*)&sB[64 + lrow][lcc] = b1;
        __syncthreads();
        bhalf8 af[4], bfr[4];
        #pragma unroll
        for (int i = 0; i < 4; ++i) af[i]  = *(bhalf8*)&sA[wm + i * 16 + r16][quad * 8];
        #pragma unroll
        for (int j = 0; j < 4; ++j) bfr[j] = *(bhalf8*)&sB[wn + j * 16 + r16][quad * 8];
        #pragma unroll
        for (int i = 0; i < 4; ++i)
            #pragma unroll
            for (int j = 0; j < 4; ++j)
                acc[i][j] = mfma16(af[i], bfr[j], acc[i][j]);
    }

    #pragma unroll
    for (int i = 0; i < 4; ++i) {
        const int rbase = m0 + wm + i * 16 + quad * 4;
        #pragma unroll
        for (int rr = 0; rr < 4; ++rr) {
            float* crow = C + (size_t)(rbase + rr) * N + n0 + wn + r16;
            #pragma unroll
            for (int j = 0; j < 4; ++j) crow[j * 16] = acc[i][j][rr];
        }
    }
}

// ---------------- RoPE + repack q/k, transpose v ----------------
// qkv: (b*s, 3072) f32.  qb: (b*16+h, s, 128) bf16.  kb: (b*4+kh, s, 128) bf16.
// vt: (b*4+kh, d, s) bf16 (transposed).
__global__ __launch_bounds__(256) void rope_k(const float* __restrict__ qkv,
                                              const float* __restrict__ freqs,
                                              bhalf* __restrict__ qb,
                                              bhalf* __restrict__ kb,
                                              bhalf* __restrict__ vt) {
    const int bs = blockIdx.x;
    const int b = bs >> 11, s = bs & 2047;
    const float* row = qkv + (size_t)bs * 3072;
    const int tid = threadIdx.x;

    // Q: 4 consecutive rope pairs per thread
    {
        const int h = tid >> 4, d20 = (tid & 15) * 4;
        const float* rp = row + h * HD + d20 * 2;
        float4 e0 = *(const float4*)rp;
        float4 e1 = *(const float4*)(rp + 4);
        const float* fp = freqs + (size_t)s * 128 + d20 * 2;
        float4 f0 = *(const float4*)fp;
        float4 f1 = *(const float4*)(fp + 4);
        bhalf8 o;
        o[0] = (bhalf)(e0.x * f0.x - e0.y * f0.y); o[1] = (bhalf)(e0.x * f0.y + e0.y * f0.x);
        o[2] = (bhalf)(e0.z * f0.z - e0.w * f0.w); o[3] = (bhalf)(e0.z * f0.w + e0.w * f0.z);
        o[4] = (bhalf)(e1.x * f1.x - e1.y * f1.y); o[5] = (bhalf)(e1.x * f1.y + e1.y * f1.x);
        o[6] = (bhalf)(e1.z * f1.z - e1.w * f1.w); o[7] = (bhalf)(e1.z * f1.w + e1.w * f1.z);
        *(bhalf8*)(qb + ((size_t)(b * N_HEADS + h) * SEQ + s) * HD + d20 * 2) = o;
    }
    // K: threads 0..63 cover 4 kv heads
    if (tid < 64) {
        const int kh = tid >> 4, d20 = (tid & 15) * 4;
        const float* rp = row + 2048 + kh * HD + d20 * 2;
        float4 e0 = *(const float4*)rp;
        float4 e1 = *(const float4*)(rp + 4);
        const float* fp = freqs + (size_t)s * 128 + d20 * 2;
        float4 f0 = *(const float4*)fp;
        float4 f1 = *(const float4*)(fp + 4);
        bhalf8 o;
        o[0] = (bhalf)(e0.x * f0.x - e0.y * f0.y); o[1] = (bhalf)(e0.x * f0.y + e0.y * f0.x);
        o[2] = (bhalf)(e0.z * f0.z - e0.w * f0.w); o[3] = (bhalf)(e0.z * f0.w + e0.w * f0.z);
        o[4] = (bhalf)(e1.x * f1.x - e1.y * f1.y); o[5] = (bhalf)(e1.x * f1.y + e1.y * f1.x);
        o[6] = (bhalf)(e1.z * f1.z - e1.w * f1.w); o[7] = (bhalf)(e1.z * f1.w + e1.w * f1.z);
        *(bhalf8*)(kb + ((size_t)(b * N_KV + kh) * SEQ + s) * HD + d20 * 2) = o;
    }
    // V: transposed store (d-major), scalar
    for (int e = tid; e < 512; e += 256) {
        const int kh = e >> 7, d = e & 127;
        vt[((size_t)(b * N_KV + kh) * HD + d) * SEQ + s] = (bhalf)row[2560 + e];
    }
}

// ---------------- Flash attention ----------------
// grid: b(2) * h(16) * qtile(32) = 1024 blocks, 256 threads (4 waves x 16 q-rows)
__global__ __launch_bounds__(256) void attn_k(const bhalf* __restrict__ qb,
                                              const bhalf* __restrict__ kb,
                                              const bhalf* __restrict__ vt,
                                              bhalf* __restrict__ ob) {
    const int tid = threadIdx.x;
    const int wave = tid >> 6, lane = tid & 63;
    const int quad = lane >> 4, r16 = lane & 15;
    const int qt = blockIdx.x & 31;
    const int h = (blockIdx.x >> 5) & 15;
    const int b = blockIdx.x >> 9;
    const int kvh = h >> 2;

    __shared__ __align__(16) bhalf sK[64][136];
    __shared__ __align__(16) bhalf sV[128][72];
    __shared__ __align__(16) bhalf sP[4][16][72];

    // Q fragments held in registers (A-operand layout: m=r16, k=quad*8+j)
    const bhalf* qbase = qb + (((size_t)(b * N_HEADS + h) * SEQ) + qt * 64 + wave * 16 + r16) * HD;
    bhalf8 qf[4];
    #pragma unroll
    for (int kk = 0; kk < 4; ++kk) qf[kk] = *(const bhalf8*)(qbase + kk * 32 + quad * 8);

    f32x4 accO[8];
    #pragma unroll
    for (int dt = 0; dt < 8; ++dt) accO[dt] = (f32x4)0.0f;
    float m_i[4], l_i[4];
    #pragma unroll
    for (int r = 0; r < 4; ++r) { m_i[r] = -1e30f; l_i[r] = 0.0f; }

    const bhalf* Kbase = kb + (size_t)(b * N_KV + kvh) * SEQ * HD;
    const bhalf* Vbase = vt + (size_t)(b * N_KV + kvh) * HD * SEQ;
    const float scale = 0.08838834764831845f;   // 1/sqrt(128)

    for (int kt = 0; kt <= qt; ++kt) {
        __syncthreads();
        // stage K tile (64 keys x 128d), coalesced
        #pragma unroll
        for (int c = tid; c < 1024; c += 256) {
            const int krow = c >> 4, cc = (c & 15) * 8;
            *(bhalf8*)&sK[krow][cc] = *(const bhalf8*)(Kbase + (size_t)(kt * 64 + krow) * HD + cc);
        }
        // stage V tile transposed-source (128d x 64 keys), coalesced
        #pragma unroll
        for (int c = tid; c < 1024; c += 256) {
            const int d = c >> 3, cc = (c & 7) * 8;
            *(bhalf8*)&sV[d][cc] = *(const bhalf8*)(Vbase + (size_t)d * SEQ + kt * 64 + cc);
        }
        __syncthreads();

        // S = Q K^T  (4 key ntiles x 4 k-steps)
        f32x4 accS[4];
        #pragma unroll
        for (int nt = 0; nt < 4; ++nt) accS[nt] = (f32x4)0.0f;
        #pragma unroll
        for (int nt = 0; nt < 4; ++nt)
            #pragma unroll
            for (int kk = 0; kk < 4; ++kk) {
                bhalf8 kf = *(bhalf8*)&sK[nt * 16 + r16][kk * 32 + quad * 8];
                accS[nt] = mfma16(qf[kk], kf, accS[nt]);
            }
        #pragma unroll
        for (int nt = 0; nt < 4; ++nt)
            #pragma unroll
            for (int r = 0; r < 4; ++r) accS[nt][r] *= scale;
        if (kt == qt) {   // diagonal tile: causal mask (key > query)
            #pragma unroll
            for (int nt = 0; nt < 4; ++nt)
                #pragma unroll
                for (int r = 0; r < 4; ++r)
                    if (nt * 16 + r16 > wave * 16 + quad * 4 + r) accS[nt][r] = -1e30f;
        }

        // online softmax row stats (rows live across 16-lane groups)
        float mnew[4], alpha[4];
        #pragma unroll
        for (int r = 0; r < 4; ++r) {
            float mx = fmaxf(fmaxf(accS[0][r], accS[1][r]), fmaxf(accS[2][r], accS[3][r]));
            #pragma unroll
            for (int off = 8; off; off >>= 1) mx = fmaxf(mx, __shfl_xor(mx, off, 16));
            mnew[r] = fmaxf(m_i[r], mx);
            alpha[r] = __expf(m_i[r] - mnew[r]);
            m_i[r] = mnew[r];
        }
        float rs[4] = {0.f, 0.f, 0.f, 0.f};
        #pragma unroll
        for (int nt = 0; nt < 4; ++nt)
            #pragma unroll
            for (int r = 0; r < 4; ++r) {
                float p = __expf(accS[nt][r] - mnew[r]);
                sP[wave][quad * 4 + r][nt * 16 + r16] = (bhalf)p;
                rs[r] += p;
            }
        #pragma unroll
        for (int r = 0; r < 4; ++r) {
            float s = rs[r];
            #pragma unroll
            for (int off = 8; off; off >>= 1) s += __shfl_xor(s, off, 16);
            l_i[r] = l_i[r] * alpha[r] + s;
        }
        #pragma unroll
        for (int dt = 0; dt < 8; ++dt)
            #pragma unroll
            for (int r = 0; r < 4; ++r) accO[dt][r] *= alpha[r];

        // O += P V   (P via LDS round-trip into A-operand layout)
        #pragma unroll
        for (int kk2 = 0; kk2 < 2; ++kk2) {
            bhalf8 pf = *(bhalf8*)&sP[wave][r16][kk2 * 32 + quad * 8];
            #pragma unroll
            for (int dt = 0; dt < 8; ++dt) {
                bhalf8 vf = *(bhalf8*)&sV[dt * 16 + r16][kk2 * 32 + quad * 8];
                accO[dt] = mfma16(pf, vf, accO[dt]);
            }
        }
    }

    float inv[4];
    #pragma unroll
    for (int r = 0; r < 4; ++r) inv[r] = 1.0f / l_i[r];
    const size_t obase = ((size_t)b * SEQ + qt * 64 + wave * 16) * (size_t)(N_HEADS * HD) + h * HD;
    #pragma unroll
    for (int dt = 0; dt < 8; ++dt)
        #pragma unroll
        for (int r = 0; r < 4; ++r)
            ob[obase + (size_t)(quad * 4 + r) * (N_HEADS * HD) + dt * 16 + r16] =
                (bhalf)(accO[dt][r] * inv[r]);
}

extern "C" void kernel_launch(void* const* d_in, const int* in_sizes, int n_in,
                              void* d_out, int out_size, void* d_ws, size_t ws_size,
                              hipStream_t stream) {
    const float* x      = (const float*)d_in[0];
    const float* freqs  = (const float*)d_in[1];
    const float* norm_w = (const float*)d_in[2];
    const float* wqkv   = (const float*)d_in[3];
    const float* wo     = (const float*)d_in[4];
    float* out = (float*)d_out;

    char* ws = (char*)d_ws;
    bhalf* wqkv_b = (bhalf*)(ws);                      // 3072*2048*2 = 12,582,912
    bhalf* wo_b   = (bhalf*)(ws + 12582912);           //  8,388,608
    bhalf* xn     = (bhalf*)(ws + 20971520);           // 16,777,216
    float* qkv    = (float*)(ws + 37748736);           // 50,331,648
    bhalf* qb     = (bhalf*)(ws + 88080384);           // 16,777,216
    bhalf* kb     = (bhalf*)(ws + 104857600);          //  4,194,304
    bhalf* vtb    = (bhalf*)(ws + 109051904);          //  4,194,304
    bhalf* attn   = (bhalf*)(ws + 113246208);          // 16,777,216 (end 130,023,424)

    cvt_w<<<10240, 256, 0, stream>>>(wqkv, wo, wqkv_b);
    rmsnorm_k<<<BATCH * SEQ, 256, 0, stream>>>(x, norm_w, xn);
    gemm_abt<<<dim3(24, 32), 256, 0, stream>>>(xn, wqkv_b, qkv, 3072, 2048);
    rope_k<<<BATCH * SEQ, 256, 0, stream>>>(qkv, freqs, qb, kb, vtb);
    attn_k<<<1024, 256, 0, stream>>>(qb, kb, vtb, attn);
    gemm_abt<<<dim3(16, 32), 256, 0, stream>>>(attn, wo_b, out, 2048, 2048);
}

// Round 2
// 370.330 us; speedup vs baseline: 1.3577x; 1.3577x over previous
//
#include <hip/hip_runtime.h>
#include <cstdint>
#include <cstddef>

typedef __bf16 bhalf;
typedef __bf16 bhalf8 __attribute__((ext_vector_type(8)));
typedef __bf16 bhalf4 __attribute__((ext_vector_type(4)));
typedef float f32x4 __attribute__((ext_vector_type(4)));

#define RMS_EPS 1e-6f
#define N_HEADS 16
#define N_KV 4
#define HD 128
#define DIM 2048
#define SEQ 2048
#define BATCH 2

static __device__ __forceinline__ f32x4 mfma16(bhalf8 a, bhalf8 b, f32x4 c) {
    return __builtin_amdgcn_mfma_f32_16x16x32_bf16(a, b, c, 0, 0, 0);
}

// ---------------- weight convert f32 -> bf16 ----------------
__global__ __launch_bounds__(256) void cvt_w(const float* __restrict__ a,
                                             const float* __restrict__ b,
                                             bhalf* __restrict__ dst) {
    size_t i = ((size_t)blockIdx.x * 256 + threadIdx.x) * 4;
    const size_t NQ = (size_t)3072 * 2048;
    float4 v = (i < NQ) ? ((const float4*)a)[i >> 2] : ((const float4*)b)[(i - NQ) >> 2];
    bhalf4 o;
    o[0] = (bhalf)v.x; o[1] = (bhalf)v.y; o[2] = (bhalf)v.z; o[3] = (bhalf)v.w;
    *(bhalf4*)(dst + i) = o;
}

// ---------------- RMSNorm: one block per row ----------------
__global__ __launch_bounds__(256) void rmsnorm_k(const float* __restrict__ x,
                                                 const float* __restrict__ w,
                                                 bhalf* __restrict__ xn) {
    const int row = blockIdx.x;
    const int tid = threadIdx.x;
    const float4* xr = (const float4*)(x + (size_t)row * DIM);
    float4 v0 = xr[tid * 2], v1 = xr[tid * 2 + 1];
    float ss = v0.x * v0.x + v0.y * v0.y + v0.z * v0.z + v0.w * v0.w
             + v1.x * v1.x + v1.y * v1.y + v1.z * v1.z + v1.w * v1.w;
    #pragma unroll
    for (int off = 32; off; off >>= 1) ss += __shfl_xor(ss, off, 64);
    __shared__ float red[4];
    if ((tid & 63) == 0) red[tid >> 6] = ss;
    __syncthreads();
    float tot = red[0] + red[1] + red[2] + red[3];
    float scale = rsqrtf(tot * (1.0f / DIM) + RMS_EPS);
    const float4* wr = (const float4*)w;
    float4 w0 = wr[tid * 2], w1 = wr[tid * 2 + 1];
    bhalf8 o;
    o[0] = (bhalf)(v0.x * scale * w0.x); o[1] = (bhalf)(v0.y * scale * w0.y);
    o[2] = (bhalf)(v0.z * scale * w0.z); o[3] = (bhalf)(v0.w * scale * w0.w);
    o[4] = (bhalf)(v1.x * scale * w1.x); o[5] = (bhalf)(v1.y * scale * w1.y);
    o[6] = (bhalf)(v1.z * scale * w1.z); o[7] = (bhalf)(v1.w * scale * w1.w);
    *(bhalf8*)(xn + (size_t)row * DIM + tid * 8) = o;
}

// ---------------- GEMM C = A * B^T (both K-contiguous, bf16 in, f32 out) ---
// A: M x K, B: N x K, C: M x N.  Tile 128x128, BK=32, 4 waves (2x2 of 64x64).
__global__ __launch_bounds__(256) void gemm_abt(const bhalf* __restrict__ A,
                                                const bhalf* __restrict__ B,
                                                float* __restrict__ C,
                                                int N, int K) {
    const int tid = threadIdx.x;
    const int wave = tid >> 6, lane = tid & 63;
    const int quad = lane >> 4, r16 = lane & 15;
    const int m0 = blockIdx.y * 128, n0 = blockIdx.x * 128;
    const int wm = (wave >> 1) * 64, wn = (wave & 1) * 64;

    __shared__ __align__(16) bhalf sA[128][40];
    __shared__ __align__(16) bhalf sB[128][40];

    f32x4 acc[4][4];
    #pragma unroll
    for (int i = 0; i < 4; ++i)
        #pragma unroll
        for (int j = 0; j < 4; ++j) acc[i][j] = (f32x4)0.0f;

    const int lrow = tid >> 2, lcc = (tid & 3) * 8;
    const bhalf* a0p = A + (size_t)(m0 + lrow) * K + lcc;
    const bhalf* a1p = a0p + (size_t)64 * K;
    const bhalf* b0p = B + (size_t)(n0 + lrow) * K + lcc;
    const bhalf* b1p = b0p + (size_t)64 * K;

    for (int k0 = 0; k0 < K; k0 += 32) {
        bhalf8 a0 = *(const bhalf8*)(a0p + k0);
        bhalf8 a1 = *(const bhalf8*)(a1p + k0);
        bhalf8 b0 = *(const bhalf8*)(b0p + k0);
        bhalf8 b1 = *(const bhalf8*)(b1p + k0);
        __syncthreads();
        *(bhalf8*)&sA[lrow][lcc] = a0;
        *(bhalf8*)&sA[64 + lrow][lcc] = a1;
        *(bhalf8*)&sB[lrow][lcc] = b0;
        *(bhalf8*)&sB[64 + lrow][lcc] = b1;
        __syncthreads();
        bhalf8 af[4], bfr[4];
        #pragma unroll
        for (int i = 0; i < 4; ++i) af[i]  = *(bhalf8*)&sA[wm + i * 16 + r16][quad * 8];
        #pragma unroll
        for (int j = 0; j < 4; ++j) bfr[j] = *(bhalf8*)&sB[wn + j * 16 + r16][quad * 8];
        #pragma unroll
        for (int i = 0; i < 4; ++i)
            #pragma unroll
            for (int j = 0; j < 4; ++j)
                acc[i][j] = mfma16(af[i], bfr[j], acc[i][j]);
    }

    #pragma unroll
    for (int i = 0; i < 4; ++i) {
        const int rbase = m0 + wm + i * 16 + quad * 4;
        #pragma unroll
        for (int rr = 0; rr < 4; ++rr) {
            float* crow = C + (size_t)(rbase + rr) * N + n0 + wn + r16;
            #pragma unroll
            for (int j = 0; j < 4; ++j) crow[j * 16] = acc[i][j][rr];
        }
    }
}

// ---------------- RoPE + repack q/k, transpose v ----------------
__global__ __launch_bounds__(256) void rope_k(const float* __restrict__ qkv,
                                              const float* __restrict__ freqs,
                                              bhalf* __restrict__ qb,
                                              bhalf* __restrict__ kb,
                                              bhalf* __restrict__ vt) {
    const int bs = blockIdx.x;
    const int b = bs >> 11, s = bs & 2047;
    const float* row = qkv + (size_t)bs * 3072;
    const int tid = threadIdx.x;

    {
        const int h = tid >> 4, d20 = (tid & 15) * 4;
        const float* rp = row + h * HD + d20 * 2;
        float4 e0 = *(const float4*)rp;
        float4 e1 = *(const float4*)(rp + 4);
        const float* fp = freqs + (size_t)s * 128 + d20 * 2;
        float4 f0 = *(const float4*)fp;
        float4 f1 = *(const float4*)(fp + 4);
        bhalf8 o;
        o[0] = (bhalf)(e0.x * f0.x - e0.y * f0.y); o[1] = (bhalf)(e0.x * f0.y + e0.y * f0.x);
        o[2] = (bhalf)(e0.z * f0.z - e0.w * f0.w); o[3] = (bhalf)(e0.z * f0.w + e0.w * f0.z);
        o[4] = (bhalf)(e1.x * f1.x - e1.y * f1.y); o[5] = (bhalf)(e1.x * f1.y + e1.y * f1.x);
        o[6] = (bhalf)(e1.z * f1.z - e1.w * f1.w); o[7] = (bhalf)(e1.z * f1.w + e1.w * f1.z);
        *(bhalf8*)(qb + ((size_t)(b * N_HEADS + h) * SEQ + s) * HD + d20 * 2) = o;
    }
    if (tid < 64) {
        const int kh = tid >> 4, d20 = (tid & 15) * 4;
        const float* rp = row + 2048 + kh * HD + d20 * 2;
        float4 e0 = *(const float4*)rp;
        float4 e1 = *(const float4*)(rp + 4);
        const float* fp = freqs + (size_t)s * 128 + d20 * 2;
        float4 f0 = *(const float4*)fp;
        float4 f1 = *(const float4*)(fp + 4);
        bhalf8 o;
        o[0] = (bhalf)(e0.x * f0.x - e0.y * f0.y); o[1] = (bhalf)(e0.x * f0.y + e0.y * f0.x);
        o[2] = (bhalf)(e0.z * f0.z - e0.w * f0.w); o[3] = (bhalf)(e0.z * f0.w + e0.w * f0.z);
        o[4] = (bhalf)(e1.x * f1.x - e1.y * f1.y); o[5] = (bhalf)(e1.x * f1.y + e1.y * f1.x);
        o[6] = (bhalf)(e1.z * f1.z - e1.w * f1.w); o[7] = (bhalf)(e1.z * f1.w + e1.w * f1.z);
        *(bhalf8*)(kb + ((size_t)(b * N_KV + kh) * SEQ + s) * HD + d20 * 2) = o;
    }
    for (int e = tid; e < 512; e += 256) {
        const int kh = e >> 7, d = e & 127;
        vt[((size_t)(b * N_KV + kh) * HD + d) * SEQ + s] = (bhalf)row[2560 + e];
    }
}

// ---------------- Flash attention (balanced pairs + reg-prefetch pipeline) --
// grid: b(2) * h(16) * pair(16) = 512 blocks; block handles q-tiles p and 31-p
// (each block: exactly 33 kt-iterations). 256 threads = 4 waves x 16 q-rows.
__global__ __launch_bounds__(256, 2) void attn_k(const bhalf* __restrict__ qb,
                                                 const bhalf* __restrict__ kb,
                                                 const bhalf* __restrict__ vt,
                                                 bhalf* __restrict__ ob) {
    const int tid = threadIdx.x;
    const int wave = tid >> 6, lane = tid & 63;
    const int quad = lane >> 4, r16 = lane & 15;
    const int pair = blockIdx.x & 15;
    const int h = (blockIdx.x >> 4) & 15;
    const int b = blockIdx.x >> 8;
    const int kvh = h >> 2;

    __shared__ __align__(16) bhalf sK[64][136];
    __shared__ __align__(16) bhalf sV[128][72];
    __shared__ __align__(16) bhalf sP[4][16][72];

    const bhalf* Kbase = kb + (size_t)(b * N_KV + kvh) * SEQ * HD;
    const bhalf* Vbase = vt + (size_t)(b * N_KV + kvh) * HD * SEQ;
    // scale * log2(e): softmax computed in base-2 domain, folded into Q frags
    const float SCL2 = 0.08838834764831845f * 1.4426950408889634f;

    // staging address components (constant per thread)
    const int kr = tid >> 4, kc = (tid & 15) * 8;   // K: rows kr+16i, col kc
    const int vr = tid >> 3, vc = (tid & 7) * 8;    // V^T: rows vr+32i, col vc

    for (int phase = 0; phase < 2; ++phase) {
        const int qt = phase ? (31 - pair) : pair;

        // Q fragments (A-operand layout), scale folded in
        const bhalf* qbase = qb + (((size_t)(b * N_HEADS + h) * SEQ) + qt * 64 + wave * 16 + r16) * HD;
        bhalf8 qf[4];
        #pragma unroll
        for (int kk = 0; kk < 4; ++kk) {
            bhalf8 q0 = *(const bhalf8*)(qbase + kk * 32 + quad * 8);
            #pragma unroll
            for (int e = 0; e < 8; ++e) q0[e] = (bhalf)((float)q0[e] * SCL2);
            qf[kk] = q0;
        }

        f32x4 accO[8];
        #pragma unroll
        for (int dt = 0; dt < 8; ++dt) accO[dt] = (f32x4)0.0f;
        float m_i[4], l_i[4];
        #pragma unroll
        for (int r = 0; r < 4; ++r) { m_i[r] = -1e30f; l_i[r] = 0.0f; }

        // preload tile 0 into registers
        bhalf8 kreg[4], vreg[4];
        #pragma unroll
        for (int i = 0; i < 4; ++i) {
            kreg[i] = *(const bhalf8*)(Kbase + (size_t)(kr + 16 * i) * HD + kc);
            vreg[i] = *(const bhalf8*)(Vbase + (size_t)(vr + 32 * i) * SEQ + vc);
        }

        for (int kt = 0; kt <= qt; ++kt) {
            __syncthreads();   // previous iteration's LDS reads complete
            #pragma unroll
            for (int i = 0; i < 4; ++i) {
                *(bhalf8*)&sK[kr + 16 * i][kc] = kreg[i];
                *(bhalf8*)&sV[vr + 32 * i][vc] = vreg[i];
            }
            __syncthreads();
            // issue next tile's loads now; latency hides behind compute
            if (kt < qt) {
                const int kn = (kt + 1) * 64;
                #pragma unroll
                for (int i = 0; i < 4; ++i) {
                    kreg[i] = *(const bhalf8*)(Kbase + (size_t)(kn + kr + 16 * i) * HD + kc);
                    vreg[i] = *(const bhalf8*)(Vbase + (size_t)(vr + 32 * i) * SEQ + kn + vc);
                }
            }

            // S = Q K^T (already in base-2 log domain via folded scale)
            f32x4 accS[4];
            #pragma unroll
            for (int nt = 0; nt < 4; ++nt) accS[nt] = (f32x4)0.0f;
            #pragma unroll
            for (int nt = 0; nt < 4; ++nt)
                #pragma unroll
                for (int kk = 0; kk < 4; ++kk) {
                    bhalf8 kf = *(bhalf8*)&sK[nt * 16 + r16][kk * 32 + quad * 8];
                    accS[nt] = mfma16(qf[kk], kf, accS[nt]);
                }
            if (kt == qt) {   // diagonal tile: causal mask (key > query)
                #pragma unroll
                for (int nt = 0; nt < 4; ++nt)
                    #pragma unroll
                    for (int r = 0; r < 4; ++r)
                        if (nt * 16 + r16 > wave * 16 + quad * 4 + r) accS[nt][r] = -1e30f;
            }

            // online softmax (base-2)
            float mnew[4], alpha[4];
            #pragma unroll
            for (int r = 0; r < 4; ++r) {
                float mx = fmaxf(fmaxf(accS[0][r], accS[1][r]), fmaxf(accS[2][r], accS[3][r]));
                #pragma unroll
                for (int off = 8; off; off >>= 1) mx = fmaxf(mx, __shfl_xor(mx, off, 16));
                mnew[r] = fmaxf(m_i[r], mx);
                alpha[r] = exp2f(m_i[r] - mnew[r]);
                m_i[r] = mnew[r];
            }
            float rs[4] = {0.f, 0.f, 0.f, 0.f};
            #pragma unroll
            for (int nt = 0; nt < 4; ++nt)
                #pragma unroll
                for (int r = 0; r < 4; ++r) {
                    float p = exp2f(accS[nt][r] - mnew[r]);
                    sP[wave][quad * 4 + r][nt * 16 + r16] = (bhalf)p;
                    rs[r] += p;
                }
            #pragma unroll
            for (int r = 0; r < 4; ++r) {
                float s = rs[r];
                #pragma unroll
                for (int off = 8; off; off >>= 1) s += __shfl_xor(s, off, 16);
                l_i[r] = l_i[r] * alpha[r] + s;
            }
            #pragma unroll
            for (int dt = 0; dt < 8; ++dt)
                #pragma unroll
                for (int r = 0; r < 4; ++r) accO[dt][r] *= alpha[r];

            // O += P V (P via LDS round-trip into A-operand layout)
            #pragma unroll
            for (int kk2 = 0; kk2 < 2; ++kk2) {
                bhalf8 pf = *(bhalf8*)&sP[wave][r16][kk2 * 32 + quad * 8];
                #pragma unroll
                for (int dt = 0; dt < 8; ++dt) {
                    bhalf8 vf = *(bhalf8*)&sV[dt * 16 + r16][kk2 * 32 + quad * 8];
                    accO[dt] = mfma16(pf, vf, accO[dt]);
                }
            }
        }

        float inv[4];
        #pragma unroll
        for (int r = 0; r < 4; ++r) inv[r] = 1.0f / l_i[r];
        const size_t obase = ((size_t)b * SEQ + qt * 64 + wave * 16) * (size_t)(N_HEADS * HD) + h * HD;
        #pragma unroll
        for (int dt = 0; dt < 8; ++dt)
            #pragma unroll
            for (int r = 0; r < 4; ++r)
                ob[obase + (size_t)(quad * 4 + r) * (N_HEADS * HD) + dt * 16 + r16] =
                    (bhalf)(accO[dt][r] * inv[r]);
    }
}

extern "C" void kernel_launch(void* const* d_in, const int* in_sizes, int n_in,
                              void* d_out, int out_size, void* d_ws, size_t ws_size,
                              hipStream_t stream) {
    const float* x      = (const float*)d_in[0];
    const float* freqs  = (const float*)d_in[1];
    const float* norm_w = (const float*)d_in[2];
    const float* wqkv   = (const float*)d_in[3];
    const float* wo     = (const float*)d_in[4];
    float* out = (float*)d_out;

    char* ws = (char*)d_ws;
    bhalf* wqkv_b = (bhalf*)(ws);                      // 3072*2048*2 = 12,582,912
    bhalf* wo_b   = (bhalf*)(ws + 12582912);           //  8,388,608
    bhalf* xn     = (bhalf*)(ws + 20971520);           // 16,777,216
    float* qkv    = (float*)(ws + 37748736);           // 50,331,648
    bhalf* qb     = (bhalf*)(ws + 88080384);           // 16,777,216
    bhalf* kb     = (bhalf*)(ws + 104857600);          //  4,194,304
    bhalf* vtb    = (bhalf*)(ws + 109051904);          //  4,194,304
    bhalf* attn   = (bhalf*)(ws + 113246208);          // 16,777,216 (end 130,023,424)

    cvt_w<<<10240, 256, 0, stream>>>(wqkv, wo, wqkv_b);
    rmsnorm_k<<<BATCH * SEQ, 256, 0, stream>>>(x, norm_w, xn);
    gemm_abt<<<dim3(24, 32), 256, 0, stream>>>(xn, wqkv_b, qkv, 3072, 2048);
    rope_k<<<BATCH * SEQ, 256, 0, stream>>>(qkv, freqs, qb, kb, vtb);
    attn_k<<<512, 256, 0, stream>>>(qb, kb, vtb, attn);
    gemm_abt<<<dim3(16, 32), 256, 0, stream>>>(attn, wo_b, out, 2048, 2048);
}